// Round 15
// baseline (236.652 us; speedup 1.0000x reference)
//
#include <hip/hip_runtime.h>
#include <hip/hip_bf16.h>

typedef __hip_bfloat16 bf16;
typedef __attribute__((ext_vector_type(8))) short short8;
typedef __attribute__((ext_vector_type(4))) float f32x4;

#define D_EMB 384
#define NHEAD 6
#define HDIM 64
#define SEQ 256
#define BATCH 64
#define M_ROWS (BATCH * SEQ)   // 16384
#define DFF (4 * D_EMB)        // 1536
#define DQKV (3 * D_EMB)       // 1152

__device__ __forceinline__ void async_load16(const void* gptr, void* lptr) {
    __builtin_amdgcn_global_load_lds(
        (const __attribute__((address_space(1))) unsigned int*)gptr,
        (__attribute__((address_space(3))) unsigned int*)lptr, 16, 0, 0);
}

// ---------------------------------------------------------------------------
// Combined weight prep: all six f32 [K,N] -> bf16 [N,K] transposes in ONE dispatch.
// ---------------------------------------------------------------------------
__global__ __launch_bounds__(256)
void transpose_all(const float* __restrict__ wq, const float* __restrict__ wk,
                   const float* __restrict__ wv, const float* __restrict__ wo,
                   const float* __restrict__ w1, const float* __restrict__ w2,
                   bf16* __restrict__ wqkv_t, bf16* __restrict__ wo_t,
                   bf16* __restrict__ w1_t, bf16* __restrict__ w2_t)
{
    __shared__ float t[32][33];
    const int id = blockIdx.x;
    const float* src; bf16* dst; int K, N, local, nbT;
    if      (id <  144) { src = wq; dst = wqkv_t;               K = 384;  N = 384;  local = id;        nbT = 12; }
    else if (id <  288) { src = wk; dst = wqkv_t + 147456;      K = 384;  N = 384;  local = id - 144;  nbT = 12; }
    else if (id <  432) { src = wv; dst = wqkv_t + 294912;      K = 384;  N = 384;  local = id - 288;  nbT = 12; }
    else if (id <  576) { src = wo; dst = wo_t;                 K = 384;  N = 384;  local = id - 432;  nbT = 12; }
    else if (id < 1152) { src = w1; dst = w1_t;                 K = 384;  N = 1536; local = id - 576;  nbT = 48; }
    else                { src = w2; dst = w2_t;                 K = 1536; N = 384;  local = id - 1152; nbT = 12; }
    const int nb = (local % nbT) * 32, kb = (local / nbT) * 32;
    const int tx = threadIdx.x, ty = threadIdx.y;
#pragma unroll
    for (int i = 0; i < 32; i += 8)
        t[ty + i][tx] = src[(size_t)(kb + ty + i) * N + nb + tx];
    __syncthreads();
#pragma unroll
    for (int i = 0; i < 32; i += 8)
        dst[(size_t)(nb + ty + i) * K + kb + tx] = __float2bfloat16(t[tx][ty + i]);
}

// ---------------------------------------------------------------------------
// LayerNorm: fp32 [M,384] -> bf16 [M,384]. One wave per row. (LN1 only.)
// ---------------------------------------------------------------------------
__global__ __launch_bounds__(256)
void ln_kernel(const float* __restrict__ x, const float* __restrict__ g,
               const float* __restrict__ be, bf16* __restrict__ out)
{
    const int row  = blockIdx.x * 4 + (threadIdx.x >> 6);
    const int lane = threadIdx.x & 63;
    const float* xr = x + (size_t)row * D_EMB;

    float v[6];
    float s = 0.f;
#pragma unroll
    for (int i = 0; i < 6; ++i) { v[i] = xr[lane + i * 64]; s += v[i]; }
#pragma unroll
    for (int off = 32; off; off >>= 1) s += __shfl_xor(s, off, 64);
    const float mean = s * (1.f / 384.f);

    float var = 0.f;
#pragma unroll
    for (int i = 0; i < 6; ++i) { float d = v[i] - mean; var += d * d; }
#pragma unroll
    for (int off = 32; off; off >>= 1) var += __shfl_xor(var, off, 64);
    const float rstd = rsqrtf(var * (1.f / 384.f) + 1e-5f);

    bf16* orow = out + (size_t)row * D_EMB;
#pragma unroll
    for (int i = 0; i < 6; ++i) {
        const int c = lane + i * 64;
        orow[c] = __float2bfloat16((v[i] - mean) * rstd * g[c] + be[c]);
    }
}

// ---------------------------------------------------------------------------
// MFMA GEMM (BM=128) at 512 threads / 8 waves (R23). 128x128 tile, 64 KB LDS,
// XOR swizzles, XCD chunked block swizzle. Used for qkv (VT path).
// ---------------------------------------------------------------------------
template<bool RELU, bool OUT_BF16, bool VT>
__global__ __launch_bounds__(512)
void mfma_gemm(const bf16* __restrict__ A, const bf16* __restrict__ Bt,
               const float* __restrict__ bias, const float* __restrict__ res,
               void* __restrict__ Cout, int M, int N, int K, bf16* __restrict__ vt)
{
    __shared__ __attribute__((aligned(16))) unsigned short smem[32768]; // 64 KB
    unsigned short* As = smem;           // [2][128*64]
    unsigned short* Bs = smem + 16384;   // [2][128*64]

    const int tid  = threadIdx.x;
    const int wave = tid >> 6;           // 0..7
    const int lane = tid & 63;

    // XCD-aware bijective chunked swizzle (nwg % 8 == 0 for all grids used)
    const int nwg = gridDim.x * gridDim.y;
    const int bl  = blockIdx.y * gridDim.x + blockIdx.x;
    const int lb  = (bl & 7) * (nwg >> 3) + (bl >> 3);
    const int m0  = (lb / gridDim.x) * 128;
    const int n0  = (lb % gridDim.x) * 128;

    const int wm = (wave >> 2) * 64;     // 0 or 64
    const int wn = (wave & 3) * 32;      // 0,32,64,96
    const int c16 = lane & 15;
    const int g   = lane >> 4;
    const int lr  = lane >> 3;
    const int ls  = lane & 7;

    f32x4 acc[4][2];
#pragma unroll
    for (int i = 0; i < 4; ++i)
#pragma unroll
        for (int j = 0; j < 2; ++j)
            acc[i][j] = (f32x4){0.f, 0.f, 0.f, 0.f};

    auto stage = [&](int buf, int k0) {
#pragma unroll
        for (int it = 0; it < 2; ++it) {
            const int r = (it * 8 + wave) * 8 + lr;       // rows 0..127
            const int oct = ls ^ (r & 7);
            async_load16(A + (size_t)(m0 + r) * K + k0 + oct * 8,
                         &As[buf * 8192 + (it * 8 + wave) * 512]);
            async_load16(Bt + (size_t)(n0 + r) * K + k0 + oct * 8,
                         &Bs[buf * 8192 + (it * 8 + wave) * 512]);
        }
    };

    stage(0, 0);
    const int KT = K >> 6;
    for (int kt = 0; kt < KT; ++kt) {
        const int cur = kt & 1;
        __syncthreads();
        if (kt + 1 < KT) stage(cur ^ 1, (kt + 1) * 64);
#pragma unroll
        for (int kk = 0; kk < 2; ++kk) {
            short8 af[4], bfr[2];
#pragma unroll
            for (int i = 0; i < 4; ++i) {
                const int row = wm + i * 16 + c16;
                af[i] = *(const short8*)&As[cur * 8192 + row * 64 + (((kk * 4 + g) ^ (row & 7)) << 3)];
            }
#pragma unroll
            for (int j = 0; j < 2; ++j) {
                const int row = wn + j * 16 + c16;
                bfr[j] = *(const short8*)&Bs[cur * 8192 + row * 64 + (((kk * 4 + g) ^ (row & 7)) << 3)];
            }
#pragma unroll
            for (int i = 0; i < 4; ++i)
#pragma unroll
                for (int j = 0; j < 2; ++j)
                    acc[i][j] = __builtin_amdgcn_mfma_f32_16x16x32_bf16(
                        af[i], bfr[j], acc[i][j], 0, 0, 0);
        }
    }

    const int crow = g * 4;

    if (VT && n0 >= 768) {
        // ---- V tile: LDS transpose (col-major, oct XOR-swizzled) -> vt
        __syncthreads();
        unsigned short* T = smem;            // 128*128 ushorts = 32 KB
#pragma unroll
        for (int j = 0; j < 2; ++j) {
            const int col = wn + j * 16 + c16;
#pragma unroll
            for (int i = 0; i < 4; ++i)
#pragma unroll
                for (int r = 0; r < 4; ++r) {
                    const int row = wm + i * 16 + crow + r;
                    bf16 pb = __float2bfloat16(acc[i][j][r]);
                    T[col * 128 + ((((row >> 3) ^ (col & 15)) << 3) | (row & 7))] =
                        *(unsigned short*)&pb;
                }
        }
        __syncthreads();
        const int b  = m0 >> 8;
        const int s0 = m0 & 255;
#pragma unroll
        for (int it = 0; it < 4; ++it) {
            const int cc = it * 512 + tid;                  // 0..2047
            const int col = cc >> 4, o = cc & 15;
            const int gcol = n0 - 768 + col;
            const int h = gcol >> 6, d = gcol & 63;
            const int so = (o ^ (col & 15)) << 3;
            const uint4 v = *(const uint4*)&T[col * 128 + o * 8];
            *(uint4*)(vt + (((size_t)(b * NHEAD + h) * 64 + d) * 256 + s0 + so)) = v;
        }
        return;
    }

    if (OUT_BF16) {
        // ---- coalesced bf16 epilogue via LDS restage
        __syncthreads();
        unsigned short* Cs = smem;           // 128*128 ushorts = 32 KB
#pragma unroll
        for (int j = 0; j < 2; ++j) {
            const int col = wn + j * 16 + c16;              // 0..127 in tile
            const float bv = bias ? bias[n0 + col] : 0.f;
#pragma unroll
            for (int i = 0; i < 4; ++i)
#pragma unroll
                for (int r = 0; r < 4; ++r) {
                    const int row = wm + i * 16 + crow + r;
                    float v = acc[i][j][r] + bv;
                    if (RELU) v = fmaxf(v, 0.f);
                    bf16 pb = __float2bfloat16(v);
                    Cs[row * 128 + ((((col >> 3) ^ (row & 15)) << 3) | (col & 7))] =
                        *(unsigned short*)&pb;
                }
        }
        __syncthreads();
#pragma unroll
        for (int it = 0; it < 4; ++it) {
            const int cc = it * 512 + tid;
            const int row = cc >> 4, o = cc & 15;
            const uint4 v = *(const uint4*)&Cs[row * 128 + ((o ^ (row & 15)) << 3)];
            *(uint4*)((bf16*)Cout + (size_t)(m0 + row) * N + n0 + o * 8) = v;
        }
        return;
    }

    // ---- f32 epilogue (sector-aligned). res may alias Cout.
#pragma unroll
    for (int j = 0; j < 2; ++j) {
        const int colg = n0 + wn + j * 16 + c16;
        const float bv = bias ? bias[colg] : 0.f;
#pragma unroll
        for (int i = 0; i < 4; ++i) {
            const int rowg = m0 + wm + i * 16 + crow;
#pragma unroll
            for (int r = 0; r < 4; ++r) {
                float v = acc[i][j][r] + bv;
                if (res) v += res[(size_t)(rowg + r) * N + colg];
                if (RELU) v = fmaxf(v, 0.f);
                ((float*)Cout)[(size_t)(rowg + r) * N + colg] = v;
            }
        }
    }
}

// ---------------------------------------------------------------------------
// mfma_gemm64 (R22): 512 threads / 8 waves, 64x128 tile, 48 KB LDS,
// 3 blocks/CU = 24 waves/CU. Used for ff1, ff2.
// res may alias Cout (in-place residual accumulate).
// ---------------------------------------------------------------------------
template<bool RELU, bool OUT_BF16>
__global__ __launch_bounds__(512)
void mfma_gemm64(const bf16* __restrict__ A, const bf16* __restrict__ Bt,
                 const float* __restrict__ bias, const float* __restrict__ res,
                 void* __restrict__ Cout, int M, int N, int K)
{
    __shared__ __attribute__((aligned(16))) unsigned short smem[24576]; // 48 KB
    unsigned short* As = smem;           // [2][64*64]  = 16 KB
    unsigned short* Bs = smem + 8192;    // [2][128*64] = 32 KB

    const int tid  = threadIdx.x;
    const int wave = tid >> 6;           // 0..7
    const int lane = tid & 63;

    const int nwg = gridDim.x * gridDim.y;
    const int bl  = blockIdx.y * gridDim.x + blockIdx.x;
    const int lb  = (bl & 7) * (nwg >> 3) + (bl >> 3);
    const int m0  = (lb / gridDim.x) * 64;
    const int n0  = (lb % gridDim.x) * 128;

    const int wm = (wave >> 2) * 32;     // 0 or 32
    const int wn = (wave & 3) * 32;      // 0,32,64,96
    const int c16 = lane & 15;
    const int g   = lane >> 4;
    const int lr  = lane >> 3;
    const int ls  = lane & 7;

    f32x4 acc[2][2];
#pragma unroll
    for (int i = 0; i < 2; ++i)
#pragma unroll
        for (int j = 0; j < 2; ++j)
            acc[i][j] = (f32x4){0.f, 0.f, 0.f, 0.f};

    // per-thread: 1 A load + 2 B loads per tile
    auto stage = [&](int buf, int k0) {
        {   // A rows 0..63: 8 waves x 8 rows
            const int r = wave * 8 + lr;
            const int oct = ls ^ (r & 7);
            async_load16(A + (size_t)(m0 + r) * K + k0 + oct * 8,
                         &As[buf * 4096 + wave * 512]);
        }
#pragma unroll
        for (int it = 0; it < 2; ++it) {  // B rows 0..127: 16 chunks x 8 rows
            const int r = (it * 8 + wave) * 8 + lr;
            const int oct = ls ^ (r & 7);
            async_load16(Bt + (size_t)(n0 + r) * K + k0 + oct * 8,
                         &Bs[buf * 8192 + (it * 8 + wave) * 512]);
        }
    };

    stage(0, 0);
    const int KT = K >> 6;
    for (int kt = 0; kt < KT; ++kt) {
        const int cur = kt & 1;
        __syncthreads();
        if (kt + 1 < KT) stage(cur ^ 1, (kt + 1) * 64);
#pragma unroll
        for (int kk = 0; kk < 2; ++kk) {
            short8 af[2], bfr[2];
#pragma unroll
            for (int i = 0; i < 2; ++i) {
                const int row = wm + i * 16 + c16;
                af[i] = *(const short8*)&As[cur * 4096 + row * 64 + (((kk * 4 + g) ^ (row & 7)) << 3)];
            }
#pragma unroll
            for (int j = 0; j < 2; ++j) {
                const int row = wn + j * 16 + c16;
                bfr[j] = *(const short8*)&Bs[cur * 8192 + row * 64 + (((kk * 4 + g) ^ (row & 7)) << 3)];
            }
#pragma unroll
            for (int i = 0; i < 2; ++i)
#pragma unroll
                for (int j = 0; j < 2; ++j)
                    acc[i][j] = __builtin_amdgcn_mfma_f32_16x16x32_bf16(
                        af[i], bfr[j], acc[i][j], 0, 0, 0);
        }
    }

    const int crow = g * 4;

    if (OUT_BF16) {
        // ---- coalesced bf16 epilogue via LDS restage (64x128 = 16 KB)
        __syncthreads();
        unsigned short* Cs = smem;
#pragma unroll
        for (int j = 0; j < 2; ++j) {
            const int col = wn + j * 16 + c16;              // 0..127
            const float bv = bias ? bias[n0 + col] : 0.f;
#pragma unroll
            for (int i = 0; i < 2; ++i)
#pragma unroll
                for (int r = 0; r < 4; ++r) {
                    const int row = wm + i * 16 + crow + r; // 0..63
                    float v = acc[i][j][r] + bv;
                    if (RELU) v = fmaxf(v, 0.f);
                    bf16 pb = __float2bfloat16(v);
                    Cs[row * 128 + ((((col >> 3) ^ (row & 15)) << 3) | (col & 7))] =
                        *(unsigned short*)&pb;
                }
        }
        __syncthreads();
#pragma unroll
        for (int it = 0; it < 2; ++it) {
            const int cc = it * 512 + tid;                  // 0..1023
            const int row = cc >> 4, o = cc & 15;
            const uint4 v = *(const uint4*)&Cs[row * 128 + ((o ^ (row & 15)) << 3)];
            *(uint4*)((bf16*)Cout + (size_t)(m0 + row) * N + n0 + o * 8) = v;
        }
        return;
    }

    // ---- f32 epilogue. res may alias Cout (in-place accumulate).
#pragma unroll
    for (int j = 0; j < 2; ++j) {
        const int colg = n0 + wn + j * 16 + c16;
        const float bv = bias ? bias[colg] : 0.f;
#pragma unroll
        for (int i = 0; i < 2; ++i) {
            const int rowg = m0 + wm + i * 16 + crow;
#pragma unroll
            for (int r = 0; r < 4; ++r) {
                float v = acc[i][j][r] + bv;
                if (res) v += res[(size_t)(rowg + r) * N + colg];
                if (RELU) v = fmaxf(v, 0.f);
                ((float*)Cout)[(size_t)(rowg + r) * N + colg] = v;
            }
        }
    }
}

// ---------------------------------------------------------------------------
// oproj_ln (R20): BM=32, grid 512 = 2 blocks/CU; B single-buffered 48 KB;
// BK=64 conflict-free 8-slot XOR scheme. Fuses o-proj + residual + LN2.
// ---------------------------------------------------------------------------
__global__ __launch_bounds__(256)
void oproj_ln(const bf16* __restrict__ A, const bf16* __restrict__ Bt,
              const float* __restrict__ bo, const float* __restrict__ x,
              const float* __restrict__ g2, const float* __restrict__ be2,
              float* __restrict__ out, bf16* __restrict__ h2)
{
    __shared__ __attribute__((aligned(16))) unsigned short smem[28672]; // 56 KB
    unsigned short* As = smem;            // [2][32*64]  = 8 KB
    unsigned short* Bs = smem + 4096;     // [1][384*64] = 48 KB
    __shared__ float lnred[32][4];        // {sum,sq} x {wn=0, wn=192}

    const int tid  = threadIdx.x;
    const int wave = tid >> 6;
    const int lane = tid & 63;

    const int nwg = gridDim.x;            // 512, %8==0
    const int bl  = blockIdx.x;
    const int lb  = (bl & 7) * (nwg >> 3) + (bl >> 3);
    const int m0  = lb * 32;

    const int wm  = (wave >> 1) * 16;     // 0 or 16
    const int wn  = (wave & 1) * 192;
    const int c16 = lane & 15;
    const int g   = lane >> 4;
    const int lr  = lane >> 3;
    const int ls  = lane & 7;

    f32x4 acc[12];
#pragma unroll
    for (int j = 0; j < 12; ++j)
        acc[j] = (f32x4){0.f, 0.f, 0.f, 0.f};

    auto stageA = [&](int buf, int k0) {
        const int r = wave * 8 + lr;
        const int oct = ls ^ (r & 7);
        async_load16(A + (size_t)(m0 + r) * D_EMB + k0 + oct * 8,
                     &As[buf * 2048 + wave * 512]);
    };
    auto stageB = [&](int k0) {
#pragma unroll
        for (int it = 0; it < 12; ++it) {                 // B rows 0..383
            const int r = (it * 4 + wave) * 8 + lr;
            const int oct = ls ^ (r & 7);
            async_load16(Bt + (size_t)r * D_EMB + k0 + oct * 8,
                         &Bs[(it * 4 + wave) * 512]);
        }
    };

    stageA(0, 0);
    stageB(0);
    const int KT = D_EMB >> 6;                            // 6
    for (int kt = 0; kt < KT; ++kt) {
        const int cur = kt & 1;
        __syncthreads();                                  // A[cur], B[kt] ready
        if (kt + 1 < KT) stageA(cur ^ 1, (kt + 1) * 64);  // A prefetch (dbuf)
#pragma unroll
        for (int kk = 0; kk < 2; ++kk) {
            short8 af, bfr[12];
            {
                const int row = wm + c16;                 // 0..31
                af = *(const short8*)&As[cur * 2048 + row * 64 + (((kk * 4 + g) ^ (row & 7)) << 3)];
            }
#pragma unroll
            for (int j = 0; j < 12; ++j) {
                const int row = wn + j * 16 + c16;
                bfr[j] = *(const short8*)&Bs[row * 64 + (((kk * 4 + g) ^ (row & 7)) << 3)];
            }
#pragma unroll
            for (int j = 0; j < 12; ++j)
                acc[j] = __builtin_amdgcn_mfma_f32_16x16x32_bf16(
                    af, bfr[j], acc[j], 0, 0, 0);
        }
        if (kt + 1 < KT) {
            __syncthreads();                              // readers done with B[kt]
            stageB((kt + 1) * 64);                        // overwrite B buffer
        }
    }

    // ---- epilogue: residual + bias -> out; row stats; LN -> h2
    const int crow = g * 4;
    float rsum[4], rsq[4];
#pragma unroll
    for (int r = 0; r < 4; ++r) { rsum[r] = 0.f; rsq[r] = 0.f; }

#pragma unroll
    for (int j = 0; j < 12; ++j) {
        const int col = wn + j * 16 + c16;
        const float bv = bo[col];
        const int rowg = m0 + wm + crow;
#pragma unroll
        for (int r = 0; r < 4; ++r) {
            float v = acc[j][r] + bv + x[(size_t)(rowg + r) * D_EMB + col];
            acc[j][r] = v;
            out[(size_t)(rowg + r) * D_EMB + col] = v;
            rsum[r] += v;
            rsq[r]  += v * v;
        }
    }

    // reduce across the 16 lanes (c16) sharing each row
#pragma unroll
    for (int off = 8; off; off >>= 1) {
#pragma unroll
        for (int r = 0; r < 4; ++r) {
            rsum[r] += __shfl_xor(rsum[r], off, 64);
            rsq[r]  += __shfl_xor(rsq[r], off, 64);
        }
    }
    const int half = (wave & 1) * 2;
    if (c16 == 0) {
#pragma unroll
        for (int r = 0; r < 4; ++r) {
            const int row = wm + crow + r;                // 0..31
            lnred[row][half + 0] = rsum[r];
            lnred[row][half + 1] = rsq[r];
        }
    }
    __syncthreads();

#pragma unroll
    for (int r = 0; r < 4; ++r) {
        const int row  = wm + crow + r;
        const float s  = lnred[row][0] + lnred[row][2];
        const float q  = lnred[row][1] + lnred[row][3];
        const float mean = s * (1.f / 384.f);
        const float var  = q * (1.f / 384.f) - mean * mean;
        const float rstd = rsqrtf(var + 1e-5f);
        const size_t rb = (size_t)(m0 + row) * D_EMB;
#pragma unroll
        for (int j = 0; j < 12; ++j) {
            const int col = wn + j * 16 + c16;
            h2[rb + col] = __float2bfloat16(
                (acc[j][r] - mean) * rstd * g2[col] + be2[col]);
        }
    }
}

// ---------------------------------------------------------------------------
// R24: MFMA flash attention v4 — split K/V waitcnt (T14 issue-early at zero
// residency cost). Loads reordered all-K-then-all-V; vmcnt(8) before QK^T
// (in-order retirement: exactly the 8 K loads drained, V's 8 in flight);
// vmcnt(0) only before the PV bufV reads. V's load latency hides under
// QK^T (8 MFMA) + softmax (64 exp2/lane + cvt + ds writes). Single-buffer
// 16 KB LDS, 8 blocks/CU unchanged (R4's LDS-doubling refuted).
// ---------------------------------------------------------------------------
#define ATT_SCALE 0.18033688f   // (1/sqrt(64)) * log2(e)

__global__ __launch_bounds__(64, 2)
void attn_mfma(const bf16* __restrict__ qkv, const bf16* __restrict__ vt,
               bf16* __restrict__ ctx)
{
    __shared__ __attribute__((aligned(16))) unsigned short bufKP[4096];
    __shared__ __attribute__((aligned(16))) unsigned short bufV[4096];

    const int nb   = gridDim.x;
    const int bid0 = blockIdx.x;
    const int bid  = (bid0 & 7) * (nb >> 3) + (bid0 >> 3);
    const int bh = bid >> 2, qi = bid & 3;
    const int b = bh / NHEAD, h = bh % NHEAD;
    const int lane = threadIdx.x;
    const int g = lane >> 4;
    const int c = lane & 15;
    const int lr = lane >> 3;
    const int ls = lane & 7;

    const size_t qbase  = (size_t)b * SEQ * DQKV + (size_t)h * HDIM;
    const size_t vtbase = (size_t)bh * HDIM * SEQ;

    short8 qf[4][2];
#pragma unroll
    for (int i = 0; i < 4; ++i)
#pragma unroll
        for (int kf = 0; kf < 2; ++kf)
            qf[i][kf] = *(const short8*)(qkv + qbase +
                (size_t)(qi * 64 + i * 16 + c) * DQKV + kf * 32 + g * 8);

    short8 ones;
#pragma unroll
    for (int e = 0; e < 8; ++e) ones[e] = (short)0x3F80;

    f32x4 acc_o[4][4], acc_l[4];
#pragma unroll
    for (int i = 0; i < 4; ++i) {
        acc_l[i] = (f32x4){0.f, 0.f, 0.f, 0.f};
#pragma unroll
        for (int n = 0; n < 4; ++n)
            acc_o[i][n] = (f32x4){0.f, 0.f, 0.f, 0.f};
    }

    for (int jt = 0; jt <= qi; ++jt) {
        // all K loads first, then all V loads (issue order = retire order)
#pragma unroll
        for (int it = 0; it < 8; ++it) {
            const int row = it * 8 + lr;
            const int oct = ls ^ (row & 7);
            async_load16(qkv + qbase + (size_t)(jt * 64 + row) * DQKV + D_EMB + oct * 8,
                         bufKP + it * 512);
        }
#pragma unroll
        for (int it = 0; it < 8; ++it) {
            const int row = it * 8 + lr;
            const int oct = ls ^ (row & 7);
            async_load16(vt + vtbase + (size_t)row * SEQ + jt * 64 + oct * 8,
                         bufV + it * 512);
        }
        // K (oldest 8) drained; V's 8 still in flight, hidden under QK^T+softmax
        asm volatile("s_waitcnt vmcnt(8)" ::: "memory");

        short8 kb[2][4];
#pragma unroll
        for (int kf = 0; kf < 2; ++kf)
#pragma unroll
            for (int j = 0; j < 4; ++j) {
                const int row = j * 16 + c;
                kb[kf][j] = *(const short8*)&bufKP[row * 64 + (((kf * 4 + g) ^ (row & 7)) << 3)];
            }

        const bool diag = (jt == qi);
#pragma unroll
        for (int i = 0; i < 4; ++i) {
            f32x4 s[4];
#pragma unroll
            for (int j = 0; j < 4; ++j) s[j] = (f32x4){0.f, 0.f, 0.f, 0.f};
#pragma unroll
            for (int kf = 0; kf < 2; ++kf)
#pragma unroll
                for (int j = 0; j < 4; ++j)
                    s[j] = __builtin_amdgcn_mfma_f32_16x16x32_bf16(
                        qf[i][kf], kb[kf][j], s[j], 0, 0, 0);

#pragma unroll
            for (int r = 0; r < 4; ++r) {
                const int row = i * 16 + g * 4 + r;
#pragma unroll
                for (int j = 0; j < 4; ++j) {
                    const int col = j * 16 + c;
                    float p = exp2f(s[j][r] * ATT_SCALE);
                    if (diag && col > row) p = 0.f;
                    bf16 pb = __float2bfloat16(p);
                    bufKP[row * 64 + (((col >> 3) ^ (row & 7)) << 3) + (col & 7)] =
                        *(unsigned short*)&pb;
                }
            }
        }

        // V must be resident before PV reads
        asm volatile("s_waitcnt vmcnt(0)" ::: "memory");

#pragma unroll
        for (int kf = 0; kf < 2; ++kf) {
            short8 pa[4], vb[4];
#pragma unroll
            for (int i = 0; i < 4; ++i) {
                const int row = i * 16 + c;
                pa[i] = *(const short8*)&bufKP[row * 64 + (((kf * 4 + g) ^ (row & 7)) << 3)];
            }
#pragma unroll
            for (int n = 0; n < 4; ++n) {
                const int row = n * 16 + c;
                vb[n] = *(const short8*)&bufV[row * 64 + (((kf * 4 + g) ^ (row & 7)) << 3)];
            }
#pragma unroll
            for (int i = 0; i < 4; ++i) {
#pragma unroll
                for (int n = 0; n < 4; ++n)
                    acc_o[i][n] = __builtin_amdgcn_mfma_f32_16x16x32_bf16(
                        pa[i], vb[n], acc_o[i][n], 0, 0, 0);
                acc_l[i] = __builtin_amdgcn_mfma_f32_16x16x32_bf16(
                    pa[i], ones, acc_l[i], 0, 0, 0);
            }
        }
    }

    const size_t obase = (size_t)b * SEQ * D_EMB + (size_t)h * HDIM;
#pragma unroll
    for (int i = 0; i < 4; ++i)
#pragma unroll
        for (int r = 0; r < 4; ++r) {
            const float rl = 1.f / acc_l[i][r];
            const int row = qi * 64 + i * 16 + g * 4 + r;
#pragma unroll
            for (int n = 0; n < 4; ++n) {
                const int col = n * 16 + c;
                ctx[obase + (size_t)row * D_EMB + col] =
                    __float2bfloat16(acc_o[i][n][r] * rl);
            }
        }
}

// ---------------------------------------------------------------------------
// launch
// ---------------------------------------------------------------------------
extern "C" void kernel_launch(void* const* d_in, const int* in_sizes, int n_in,
                              void* d_out, int out_size, void* d_ws, size_t ws_size,
                              hipStream_t stream)
{
    const float* x  = (const float*)d_in[0];
    const float* wq = (const float*)d_in[1];
    const float* wk = (const float*)d_in[2];
    const float* wv = (const float*)d_in[3];
    const float* wo = (const float*)d_in[4];
    const float* bo = (const float*)d_in[5];
    const float* w1 = (const float*)d_in[6];
    const float* b1 = (const float*)d_in[7];
    const float* w2 = (const float*)d_in[8];
    const float* b2 = (const float*)d_in[9];
    const float* g1  = (const float*)d_in[10];
    const float* be1 = (const float*)d_in[11];
    const float* g2  = (const float*)d_in[12];
    const float* be2 = (const float*)d_in[13];
    float* out = (float*)d_out;
    (void)in_sizes; (void)n_in; (void)out_size; (void)ws_size;

    // weight area [0,4MB): wqkv_t@0 (864K), wo_t@1M (288K), w1_t@1.5M (1.125M),
    // w2_t@2.75M (1.125M). slotA: h1/ctx/h2. slotB: qkv+vt / ff1.
    // x2 lives in d_out (written by oproj_ln, read by ff2 in-place).
    char* w = (char*)d_ws;
    bf16* wqkv_t = (bf16*)(w);
    bf16* wo_t   = (bf16*)(w + (size_t)(1024 * 1024));
    bf16* w1_t   = (bf16*)(w + (size_t)(1536 * 1024));
    bf16* w2_t   = (bf16*)(w + (size_t)(2816 * 1024));
    char* slotA  = w + 4 * 1024 * 1024;                          // 12.58 MB
    char* slotB  = slotA + (size_t)M_ROWS * D_EMB * sizeof(bf16);// 50.33 MB

    bf16* h1  = (bf16*)slotA;
    bf16* ctx = (bf16*)slotA;
    bf16* h2  = (bf16*)slotA;   // aliases ctx: oproj_ln writes only rows it reads
    bf16* qkv = (bf16*)slotB;
    bf16* vt  = (bf16*)slotB + (size_t)M_ROWS * DQKV;  // dead once ff1 written
    bf16* ff1 = (bf16*)slotB;

    const dim3 blk(256);

    // 0) weight prep (single dispatch)
    transpose_all<<<dim3(1728), dim3(32, 8), 0, stream>>>(
        wq, wk, wv, wo, w1, w2, wqkv_t, wo_t, w1_t, w2_t);

    // 1) h1 = LN(x)
    ln_kernel<<<dim3(M_ROWS / 4), blk, 0, stream>>>(x, g1, be1, h1);

    // 2) qkv = h1 @ [wq|wk|wv]; V tiles -> vt   (512-thread, 16 waves/CU)
    mfma_gemm<false, true, true><<<dim3(DQKV / 128, M_ROWS / 128), dim3(512), 0, stream>>>(
        h1, wqkv_t, nullptr, nullptr, qkv, M_ROWS, DQKV, D_EMB, vt);

    // 3) ctx = causal_attention(qkv, vt)   (split K/V waitcnt)
    attn_mfma<<<dim3(BATCH * NHEAD * 4), dim3(64), 0, stream>>>(qkv, vt, ctx);

    // 4) out(x2) = x + ctx @ wo + bo; h2 = LN(x2)  (fused, BM=32, 512 blocks)
    oproj_ln<<<dim3(M_ROWS / 32), blk, 0, stream>>>(
        ctx, wo_t, bo, x, g2, be2, out, h2);

    // 5) ff1 = relu(h2 @ w1 + b1)   (512-thread, 8-wave, 24 waves/CU)
    mfma_gemm64<true, true><<<dim3(DFF / 128, M_ROWS / 64), dim3(512), 0, stream>>>(
        h2, w1_t, b1, nullptr, ff1, M_ROWS, DFF, D_EMB);

    // 6) out += ff1 @ w2 + b2  (512-thread direct K=1536, in-place residual)
    mfma_gemm64<false, false><<<dim3(D_EMB / 128, M_ROWS / 64), dim3(512), 0, stream>>>(
        ff1, w2_t, b2, out, out, M_ROWS, D_EMB, DFF);
}

// Round 16
// 235.084 us; speedup vs baseline: 1.0067x; 1.0067x over previous
//
#include <hip/hip_runtime.h>
#include <hip/hip_bf16.h>

typedef __hip_bfloat16 bf16;
typedef __attribute__((ext_vector_type(8))) short short8;
typedef __attribute__((ext_vector_type(4))) float f32x4;

#define D_EMB 384
#define NHEAD 6
#define HDIM 64
#define SEQ 256
#define BATCH 64
#define M_ROWS (BATCH * SEQ)   // 16384
#define DFF (4 * D_EMB)        // 1536
#define DQKV (3 * D_EMB)       // 1152

__device__ __forceinline__ void async_load16(const void* gptr, void* lptr) {
    __builtin_amdgcn_global_load_lds(
        (const __attribute__((address_space(1))) unsigned int*)gptr,
        (__attribute__((address_space(3))) unsigned int*)lptr, 16, 0, 0);
}

// ---------------------------------------------------------------------------
// Combined weight prep: all six f32 [K,N] -> bf16 [N,K] transposes in ONE dispatch.
// ---------------------------------------------------------------------------
__global__ __launch_bounds__(256)
void transpose_all(const float* __restrict__ wq, const float* __restrict__ wk,
                   const float* __restrict__ wv, const float* __restrict__ wo,
                   const float* __restrict__ w1, const float* __restrict__ w2,
                   bf16* __restrict__ wqkv_t, bf16* __restrict__ wo_t,
                   bf16* __restrict__ w1_t, bf16* __restrict__ w2_t)
{
    __shared__ float t[32][33];
    const int id = blockIdx.x;
    const float* src; bf16* dst; int K, N, local, nbT;
    if      (id <  144) { src = wq; dst = wqkv_t;               K = 384;  N = 384;  local = id;        nbT = 12; }
    else if (id <  288) { src = wk; dst = wqkv_t + 147456;      K = 384;  N = 384;  local = id - 144;  nbT = 12; }
    else if (id <  432) { src = wv; dst = wqkv_t + 294912;      K = 384;  N = 384;  local = id - 288;  nbT = 12; }
    else if (id <  576) { src = wo; dst = wo_t;                 K = 384;  N = 384;  local = id - 432;  nbT = 12; }
    else if (id < 1152) { src = w1; dst = w1_t;                 K = 384;  N = 1536; local = id - 576;  nbT = 48; }
    else                { src = w2; dst = w2_t;                 K = 1536; N = 384;  local = id - 1152; nbT = 12; }
    const int nb = (local % nbT) * 32, kb = (local / nbT) * 32;
    const int tx = threadIdx.x, ty = threadIdx.y;
#pragma unroll
    for (int i = 0; i < 32; i += 8)
        t[ty + i][tx] = src[(size_t)(kb + ty + i) * N + nb + tx];
    __syncthreads();
#pragma unroll
    for (int i = 0; i < 32; i += 8)
        dst[(size_t)(nb + ty + i) * K + kb + tx] = __float2bfloat16(t[tx][ty + i]);
}

// ---------------------------------------------------------------------------
// LayerNorm: fp32 [M,384] -> bf16 [M,384]. One wave per row. (LN1 only.)
// ---------------------------------------------------------------------------
__global__ __launch_bounds__(256)
void ln_kernel(const float* __restrict__ x, const float* __restrict__ g,
               const float* __restrict__ be, bf16* __restrict__ out)
{
    const int row  = blockIdx.x * 4 + (threadIdx.x >> 6);
    const int lane = threadIdx.x & 63;
    const float* xr = x + (size_t)row * D_EMB;

    float v[6];
    float s = 0.f;
#pragma unroll
    for (int i = 0; i < 6; ++i) { v[i] = xr[lane + i * 64]; s += v[i]; }
#pragma unroll
    for (int off = 32; off; off >>= 1) s += __shfl_xor(s, off, 64);
    const float mean = s * (1.f / 384.f);

    float var = 0.f;
#pragma unroll
    for (int i = 0; i < 6; ++i) { float d = v[i] - mean; var += d * d; }
#pragma unroll
    for (int off = 32; off; off >>= 1) var += __shfl_xor(var, off, 64);
    const float rstd = rsqrtf(var * (1.f / 384.f) + 1e-5f);

    bf16* orow = out + (size_t)row * D_EMB;
#pragma unroll
    for (int i = 0; i < 6; ++i) {
        const int c = lane + i * 64;
        orow[c] = __float2bfloat16((v[i] - mean) * rstd * g[c] + be[c]);
    }
}

// ---------------------------------------------------------------------------
// MFMA GEMM (BM=128) at 512 threads / 8 waves (R23). 128x128 tile, 64 KB LDS,
// XOR swizzles, XCD chunked block swizzle. Used for qkv (VT path).
// ---------------------------------------------------------------------------
template<bool RELU, bool OUT_BF16, bool VT>
__global__ __launch_bounds__(512)
void mfma_gemm(const bf16* __restrict__ A, const bf16* __restrict__ Bt,
               const float* __restrict__ bias, const float* __restrict__ res,
               void* __restrict__ Cout, int M, int N, int K, bf16* __restrict__ vt)
{
    __shared__ __attribute__((aligned(16))) unsigned short smem[32768]; // 64 KB
    unsigned short* As = smem;           // [2][128*64]
    unsigned short* Bs = smem + 16384;   // [2][128*64]

    const int tid  = threadIdx.x;
    const int wave = tid >> 6;           // 0..7
    const int lane = tid & 63;

    // XCD-aware bijective chunked swizzle (nwg % 8 == 0 for all grids used)
    const int nwg = gridDim.x * gridDim.y;
    const int bl  = blockIdx.y * gridDim.x + blockIdx.x;
    const int lb  = (bl & 7) * (nwg >> 3) + (bl >> 3);
    const int m0  = (lb / gridDim.x) * 128;
    const int n0  = (lb % gridDim.x) * 128;

    const int wm = (wave >> 2) * 64;     // 0 or 64
    const int wn = (wave & 3) * 32;      // 0,32,64,96
    const int c16 = lane & 15;
    const int g   = lane >> 4;
    const int lr  = lane >> 3;
    const int ls  = lane & 7;

    f32x4 acc[4][2];
#pragma unroll
    for (int i = 0; i < 4; ++i)
#pragma unroll
        for (int j = 0; j < 2; ++j)
            acc[i][j] = (f32x4){0.f, 0.f, 0.f, 0.f};

    auto stage = [&](int buf, int k0) {
#pragma unroll
        for (int it = 0; it < 2; ++it) {
            const int r = (it * 8 + wave) * 8 + lr;       // rows 0..127
            const int oct = ls ^ (r & 7);
            async_load16(A + (size_t)(m0 + r) * K + k0 + oct * 8,
                         &As[buf * 8192 + (it * 8 + wave) * 512]);
            async_load16(Bt + (size_t)(n0 + r) * K + k0 + oct * 8,
                         &Bs[buf * 8192 + (it * 8 + wave) * 512]);
        }
    };

    stage(0, 0);
    const int KT = K >> 6;
    for (int kt = 0; kt < KT; ++kt) {
        const int cur = kt & 1;
        __syncthreads();
        if (kt + 1 < KT) stage(cur ^ 1, (kt + 1) * 64);
#pragma unroll
        for (int kk = 0; kk < 2; ++kk) {
            short8 af[4], bfr[2];
#pragma unroll
            for (int i = 0; i < 4; ++i) {
                const int row = wm + i * 16 + c16;
                af[i] = *(const short8*)&As[cur * 8192 + row * 64 + (((kk * 4 + g) ^ (row & 7)) << 3)];
            }
#pragma unroll
            for (int j = 0; j < 2; ++j) {
                const int row = wn + j * 16 + c16;
                bfr[j] = *(const short8*)&Bs[cur * 8192 + row * 64 + (((kk * 4 + g) ^ (row & 7)) << 3)];
            }
#pragma unroll
            for (int i = 0; i < 4; ++i)
#pragma unroll
                for (int j = 0; j < 2; ++j)
                    acc[i][j] = __builtin_amdgcn_mfma_f32_16x16x32_bf16(
                        af[i], bfr[j], acc[i][j], 0, 0, 0);
        }
    }

    const int crow = g * 4;

    if (VT && n0 >= 768) {
        // ---- V tile: LDS transpose (col-major, oct XOR-swizzled) -> vt
        __syncthreads();
        unsigned short* T = smem;            // 128*128 ushorts = 32 KB
#pragma unroll
        for (int j = 0; j < 2; ++j) {
            const int col = wn + j * 16 + c16;
#pragma unroll
            for (int i = 0; i < 4; ++i)
#pragma unroll
                for (int r = 0; r < 4; ++r) {
                    const int row = wm + i * 16 + crow + r;
                    bf16 pb = __float2bfloat16(acc[i][j][r]);
                    T[col * 128 + ((((row >> 3) ^ (col & 15)) << 3) | (row & 7))] =
                        *(unsigned short*)&pb;
                }
        }
        __syncthreads();
        const int b  = m0 >> 8;
        const int s0 = m0 & 255;
#pragma unroll
        for (int it = 0; it < 4; ++it) {
            const int cc = it * 512 + tid;                  // 0..2047
            const int col = cc >> 4, o = cc & 15;
            const int gcol = n0 - 768 + col;
            const int h = gcol >> 6, d = gcol & 63;
            const int so = (o ^ (col & 15)) << 3;
            const uint4 v = *(const uint4*)&T[col * 128 + o * 8];
            *(uint4*)(vt + (((size_t)(b * NHEAD + h) * 64 + d) * 256 + s0 + so)) = v;
        }
        return;
    }

    if (OUT_BF16) {
        // ---- coalesced bf16 epilogue via LDS restage
        __syncthreads();
        unsigned short* Cs = smem;           // 128*128 ushorts = 32 KB
#pragma unroll
        for (int j = 0; j < 2; ++j) {
            const int col = wn + j * 16 + c16;              // 0..127 in tile
            const float bv = bias ? bias[n0 + col] : 0.f;
#pragma unroll
            for (int i = 0; i < 4; ++i)
#pragma unroll
                for (int r = 0; r < 4; ++r) {
                    const int row = wm + i * 16 + crow + r;
                    float v = acc[i][j][r] + bv;
                    if (RELU) v = fmaxf(v, 0.f);
                    bf16 pb = __float2bfloat16(v);
                    Cs[row * 128 + ((((col >> 3) ^ (row & 15)) << 3) | (col & 7))] =
                        *(unsigned short*)&pb;
                }
        }
        __syncthreads();
#pragma unroll
        for (int it = 0; it < 4; ++it) {
            const int cc = it * 512 + tid;
            const int row = cc >> 4, o = cc & 15;
            const uint4 v = *(const uint4*)&Cs[row * 128 + ((o ^ (row & 15)) << 3)];
            *(uint4*)((bf16*)Cout + (size_t)(m0 + row) * N + n0 + o * 8) = v;
        }
        return;
    }

    // ---- f32 epilogue (sector-aligned). res may alias Cout.
#pragma unroll
    for (int j = 0; j < 2; ++j) {
        const int colg = n0 + wn + j * 16 + c16;
        const float bv = bias ? bias[colg] : 0.f;
#pragma unroll
        for (int i = 0; i < 4; ++i) {
            const int rowg = m0 + wm + i * 16 + crow;
#pragma unroll
            for (int r = 0; r < 4; ++r) {
                float v = acc[i][j][r] + bv;
                if (res) v += res[(size_t)(rowg + r) * N + colg];
                if (RELU) v = fmaxf(v, 0.f);
                ((float*)Cout)[(size_t)(rowg + r) * N + colg] = v;
            }
        }
    }
}

// ---------------------------------------------------------------------------
// mfma_gemm64 (R22): 512 threads / 8 waves, 64x128 tile, 48 KB LDS,
// 3 blocks/CU = 24 waves/CU. Used for ff1, ff2.
// res may alias Cout (in-place residual accumulate).
// ---------------------------------------------------------------------------
template<bool RELU, bool OUT_BF16>
__global__ __launch_bounds__(512)
void mfma_gemm64(const bf16* __restrict__ A, const bf16* __restrict__ Bt,
                 const float* __restrict__ bias, const float* __restrict__ res,
                 void* __restrict__ Cout, int M, int N, int K)
{
    __shared__ __attribute__((aligned(16))) unsigned short smem[24576]; // 48 KB
    unsigned short* As = smem;           // [2][64*64]  = 16 KB
    unsigned short* Bs = smem + 8192;    // [2][128*64] = 32 KB

    const int tid  = threadIdx.x;
    const int wave = tid >> 6;           // 0..7
    const int lane = tid & 63;

    const int nwg = gridDim.x * gridDim.y;
    const int bl  = blockIdx.y * gridDim.x + blockIdx.x;
    const int lb  = (bl & 7) * (nwg >> 3) + (bl >> 3);
    const int m0  = (lb / gridDim.x) * 64;
    const int n0  = (lb % gridDim.x) * 128;

    const int wm = (wave >> 2) * 32;     // 0 or 32
    const int wn = (wave & 3) * 32;      // 0,32,64,96
    const int c16 = lane & 15;
    const int g   = lane >> 4;
    const int lr  = lane >> 3;
    const int ls  = lane & 7;

    f32x4 acc[2][2];
#pragma unroll
    for (int i = 0; i < 2; ++i)
#pragma unroll
        for (int j = 0; j < 2; ++j)
            acc[i][j] = (f32x4){0.f, 0.f, 0.f, 0.f};

    // per-thread: 1 A load + 2 B loads per tile
    auto stage = [&](int buf, int k0) {
        {   // A rows 0..63: 8 waves x 8 rows
            const int r = wave * 8 + lr;
            const int oct = ls ^ (r & 7);
            async_load16(A + (size_t)(m0 + r) * K + k0 + oct * 8,
                         &As[buf * 4096 + wave * 512]);
        }
#pragma unroll
        for (int it = 0; it < 2; ++it) {  // B rows 0..127: 16 chunks x 8 rows
            const int r = (it * 8 + wave) * 8 + lr;
            const int oct = ls ^ (r & 7);
            async_load16(Bt + (size_t)(n0 + r) * K + k0 + oct * 8,
                         &Bs[buf * 8192 + (it * 8 + wave) * 512]);
        }
    };

    stage(0, 0);
    const int KT = K >> 6;
    for (int kt = 0; kt < KT; ++kt) {
        const int cur = kt & 1;
        __syncthreads();
        if (kt + 1 < KT) stage(cur ^ 1, (kt + 1) * 64);
#pragma unroll
        for (int kk = 0; kk < 2; ++kk) {
            short8 af[2], bfr[2];
#pragma unroll
            for (int i = 0; i < 2; ++i) {
                const int row = wm + i * 16 + c16;
                af[i] = *(const short8*)&As[cur * 4096 + row * 64 + (((kk * 4 + g) ^ (row & 7)) << 3)];
            }
#pragma unroll
            for (int j = 0; j < 2; ++j) {
                const int row = wn + j * 16 + c16;
                bfr[j] = *(const short8*)&Bs[cur * 8192 + row * 64 + (((kk * 4 + g) ^ (row & 7)) << 3)];
            }
#pragma unroll
            for (int i = 0; i < 2; ++i)
#pragma unroll
                for (int j = 0; j < 2; ++j)
                    acc[i][j] = __builtin_amdgcn_mfma_f32_16x16x32_bf16(
                        af[i], bfr[j], acc[i][j], 0, 0, 0);
        }
    }

    const int crow = g * 4;

    if (OUT_BF16) {
        // ---- coalesced bf16 epilogue via LDS restage (64x128 = 16 KB)
        __syncthreads();
        unsigned short* Cs = smem;
#pragma unroll
        for (int j = 0; j < 2; ++j) {
            const int col = wn + j * 16 + c16;              // 0..127
            const float bv = bias ? bias[n0 + col] : 0.f;
#pragma unroll
            for (int i = 0; i < 2; ++i)
#pragma unroll
                for (int r = 0; r < 4; ++r) {
                    const int row = wm + i * 16 + crow + r; // 0..63
                    float v = acc[i][j][r] + bv;
                    if (RELU) v = fmaxf(v, 0.f);
                    bf16 pb = __float2bfloat16(v);
                    Cs[row * 128 + ((((col >> 3) ^ (row & 15)) << 3) | (col & 7))] =
                        *(unsigned short*)&pb;
                }
        }
        __syncthreads();
#pragma unroll
        for (int it = 0; it < 2; ++it) {
            const int cc = it * 512 + tid;                  // 0..1023
            const int row = cc >> 4, o = cc & 15;
            const uint4 v = *(const uint4*)&Cs[row * 128 + ((o ^ (row & 15)) << 3)];
            *(uint4*)((bf16*)Cout + (size_t)(m0 + row) * N + n0 + o * 8) = v;
        }
        return;
    }

    // ---- f32 epilogue. res may alias Cout (in-place accumulate).
#pragma unroll
    for (int j = 0; j < 2; ++j) {
        const int colg = n0 + wn + j * 16 + c16;
        const float bv = bias ? bias[colg] : 0.f;
#pragma unroll
        for (int i = 0; i < 2; ++i) {
            const int rowg = m0 + wm + i * 16 + crow;
#pragma unroll
            for (int r = 0; r < 4; ++r) {
                float v = acc[i][j][r] + bv;
                if (res) v += res[(size_t)(rowg + r) * N + colg];
                if (RELU) v = fmaxf(v, 0.f);
                ((float*)Cout)[(size_t)(rowg + r) * N + colg] = v;
            }
        }
    }
}

// ---------------------------------------------------------------------------
// oproj_ln (R20): BM=32, grid 512 = 2 blocks/CU; B single-buffered 48 KB;
// BK=64 conflict-free 8-slot XOR scheme. Fuses o-proj + residual + LN2.
// ---------------------------------------------------------------------------
__global__ __launch_bounds__(256)
void oproj_ln(const bf16* __restrict__ A, const bf16* __restrict__ Bt,
              const float* __restrict__ bo, const float* __restrict__ x,
              const float* __restrict__ g2, const float* __restrict__ be2,
              float* __restrict__ out, bf16* __restrict__ h2)
{
    __shared__ __attribute__((aligned(16))) unsigned short smem[28672]; // 56 KB
    unsigned short* As = smem;            // [2][32*64]  = 8 KB
    unsigned short* Bs = smem + 4096;     // [1][384*64] = 48 KB
    __shared__ float lnred[32][4];        // {sum,sq} x {wn=0, wn=192}

    const int tid  = threadIdx.x;
    const int wave = tid >> 6;
    const int lane = tid & 63;

    const int nwg = gridDim.x;            // 512, %8==0
    const int bl  = blockIdx.x;
    const int lb  = (bl & 7) * (nwg >> 3) + (bl >> 3);
    const int m0  = lb * 32;

    const int wm  = (wave >> 1) * 16;     // 0 or 16
    const int wn  = (wave & 1) * 192;
    const int c16 = lane & 15;
    const int g   = lane >> 4;
    const int lr  = lane >> 3;
    const int ls  = lane & 7;

    f32x4 acc[12];
#pragma unroll
    for (int j = 0; j < 12; ++j)
        acc[j] = (f32x4){0.f, 0.f, 0.f, 0.f};

    auto stageA = [&](int buf, int k0) {
        const int r = wave * 8 + lr;
        const int oct = ls ^ (r & 7);
        async_load16(A + (size_t)(m0 + r) * D_EMB + k0 + oct * 8,
                     &As[buf * 2048 + wave * 512]);
    };
    auto stageB = [&](int k0) {
#pragma unroll
        for (int it = 0; it < 12; ++it) {                 // B rows 0..383
            const int r = (it * 4 + wave) * 8 + lr;
            const int oct = ls ^ (r & 7);
            async_load16(Bt + (size_t)r * D_EMB + k0 + oct * 8,
                         &Bs[(it * 4 + wave) * 512]);
        }
    };

    stageA(0, 0);
    stageB(0);
    const int KT = D_EMB >> 6;                            // 6
    for (int kt = 0; kt < KT; ++kt) {
        const int cur = kt & 1;
        __syncthreads();                                  // A[cur], B[kt] ready
        if (kt + 1 < KT) stageA(cur ^ 1, (kt + 1) * 64);  // A prefetch (dbuf)
#pragma unroll
        for (int kk = 0; kk < 2; ++kk) {
            short8 af, bfr[12];
            {
                const int row = wm + c16;                 // 0..31
                af = *(const short8*)&As[cur * 2048 + row * 64 + (((kk * 4 + g) ^ (row & 7)) << 3)];
            }
#pragma unroll
            for (int j = 0; j < 12; ++j) {
                const int row = wn + j * 16 + c16;
                bfr[j] = *(const short8*)&Bs[row * 64 + (((kk * 4 + g) ^ (row & 7)) << 3)];
            }
#pragma unroll
            for (int j = 0; j < 12; ++j)
                acc[j] = __builtin_amdgcn_mfma_f32_16x16x32_bf16(
                    af, bfr[j], acc[j], 0, 0, 0);
        }
        if (kt + 1 < KT) {
            __syncthreads();                              // readers done with B[kt]
            stageB((kt + 1) * 64);                        // overwrite B buffer
        }
    }

    // ---- epilogue: residual + bias -> out; row stats; LN -> h2
    const int crow = g * 4;
    float rsum[4], rsq[4];
#pragma unroll
    for (int r = 0; r < 4; ++r) { rsum[r] = 0.f; rsq[r] = 0.f; }

#pragma unroll
    for (int j = 0; j < 12; ++j) {
        const int col = wn + j * 16 + c16;
        const float bv = bo[col];
        const int rowg = m0 + wm + crow;
#pragma unroll
        for (int r = 0; r < 4; ++r) {
            float v = acc[j][r] + bv + x[(size_t)(rowg + r) * D_EMB + col];
            acc[j][r] = v;
            out[(size_t)(rowg + r) * D_EMB + col] = v;
            rsum[r] += v;
            rsq[r]  += v * v;
        }
    }

    // reduce across the 16 lanes (c16) sharing each row
#pragma unroll
    for (int off = 8; off; off >>= 1) {
#pragma unroll
        for (int r = 0; r < 4; ++r) {
            rsum[r] += __shfl_xor(rsum[r], off, 64);
            rsq[r]  += __shfl_xor(rsq[r], off, 64);
        }
    }
    const int half = (wave & 1) * 2;
    if (c16 == 0) {
#pragma unroll
        for (int r = 0; r < 4; ++r) {
            const int row = wm + crow + r;                // 0..31
            lnred[row][half + 0] = rsum[r];
            lnred[row][half + 1] = rsq[r];
        }
    }
    __syncthreads();

#pragma unroll
    for (int r = 0; r < 4; ++r) {
        const int row  = wm + crow + r;
        const float s  = lnred[row][0] + lnred[row][2];
        const float q  = lnred[row][1] + lnred[row][3];
        const float mean = s * (1.f / 384.f);
        const float var  = q * (1.f / 384.f) - mean * mean;
        const float rstd = rsqrtf(var + 1e-5f);
        const size_t rb = (size_t)(m0 + row) * D_EMB;
#pragma unroll
        for (int j = 0; j < 12; ++j) {
            const int col = wn + j * 16 + c16;
            h2[rb + col] = __float2bfloat16(
                (acc[j][r] - mean) * rstd * g2[col] + be2[col]);
        }
    }
}

// ---------------------------------------------------------------------------
// MFMA flash attention v3 (R24 split-waitcnt REVERTED — it regressed +7 us;
// interleaved K/V loads + single vmcnt(0) give better issue-order MLP and
// leave the compiler free to schedule). One 64-thread block per (bh, qi),
// single-buffer 16 KB LDS -> 8 blocks/CU; TLP hides tile-load latency.
// XCD chunked swizzle colocates the 4 qi blocks of one (b,h) per XCD L2.
// ---------------------------------------------------------------------------
#define ATT_SCALE 0.18033688f   // (1/sqrt(64)) * log2(e)

__global__ __launch_bounds__(64, 2)
void attn_mfma(const bf16* __restrict__ qkv, const bf16* __restrict__ vt,
               bf16* __restrict__ ctx)
{
    __shared__ __attribute__((aligned(16))) unsigned short bufKP[4096];
    __shared__ __attribute__((aligned(16))) unsigned short bufV[4096];

    const int nb   = gridDim.x;
    const int bid0 = blockIdx.x;
    const int bid  = (bid0 & 7) * (nb >> 3) + (bid0 >> 3);
    const int bh = bid >> 2, qi = bid & 3;
    const int b = bh / NHEAD, h = bh % NHEAD;
    const int lane = threadIdx.x;
    const int g = lane >> 4;
    const int c = lane & 15;
    const int lr = lane >> 3;
    const int ls = lane & 7;

    const size_t qbase  = (size_t)b * SEQ * DQKV + (size_t)h * HDIM;
    const size_t vtbase = (size_t)bh * HDIM * SEQ;

    short8 qf[4][2];
#pragma unroll
    for (int i = 0; i < 4; ++i)
#pragma unroll
        for (int kf = 0; kf < 2; ++kf)
            qf[i][kf] = *(const short8*)(qkv + qbase +
                (size_t)(qi * 64 + i * 16 + c) * DQKV + kf * 32 + g * 8);

    short8 ones;
#pragma unroll
    for (int e = 0; e < 8; ++e) ones[e] = (short)0x3F80;

    f32x4 acc_o[4][4], acc_l[4];
#pragma unroll
    for (int i = 0; i < 4; ++i) {
        acc_l[i] = (f32x4){0.f, 0.f, 0.f, 0.f};
#pragma unroll
        for (int n = 0; n < 4; ++n)
            acc_o[i][n] = (f32x4){0.f, 0.f, 0.f, 0.f};
    }

    for (int jt = 0; jt <= qi; ++jt) {
#pragma unroll
        for (int it = 0; it < 8; ++it) {
            const int row = it * 8 + lr;
            const int oct = ls ^ (row & 7);
            async_load16(qkv + qbase + (size_t)(jt * 64 + row) * DQKV + D_EMB + oct * 8,
                         bufKP + it * 512);
            async_load16(vt + vtbase + (size_t)row * SEQ + jt * 64 + oct * 8,
                         bufV + it * 512);
        }
        asm volatile("s_waitcnt vmcnt(0)" ::: "memory");

        short8 kb[2][4];
#pragma unroll
        for (int kf = 0; kf < 2; ++kf)
#pragma unroll
            for (int j = 0; j < 4; ++j) {
                const int row = j * 16 + c;
                kb[kf][j] = *(const short8*)&bufKP[row * 64 + (((kf * 4 + g) ^ (row & 7)) << 3)];
            }

        const bool diag = (jt == qi);
#pragma unroll
        for (int i = 0; i < 4; ++i) {
            f32x4 s[4];
#pragma unroll
            for (int j = 0; j < 4; ++j) s[j] = (f32x4){0.f, 0.f, 0.f, 0.f};
#pragma unroll
            for (int kf = 0; kf < 2; ++kf)
#pragma unroll
                for (int j = 0; j < 4; ++j)
                    s[j] = __builtin_amdgcn_mfma_f32_16x16x32_bf16(
                        qf[i][kf], kb[kf][j], s[j], 0, 0, 0);

#pragma unroll
            for (int r = 0; r < 4; ++r) {
                const int row = i * 16 + g * 4 + r;
#pragma unroll
                for (int j = 0; j < 4; ++j) {
                    const int col = j * 16 + c;
                    float p = exp2f(s[j][r] * ATT_SCALE);
                    if (diag && col > row) p = 0.f;
                    bf16 pb = __float2bfloat16(p);
                    bufKP[row * 64 + (((col >> 3) ^ (row & 7)) << 3) + (col & 7)] =
                        *(unsigned short*)&pb;
                }
            }
        }

#pragma unroll
        for (int kf = 0; kf < 2; ++kf) {
            short8 pa[4], vb[4];
#pragma unroll
            for (int i = 0; i < 4; ++i) {
                const int row = i * 16 + c;
                pa[i] = *(const short8*)&bufKP[row * 64 + (((kf * 4 + g) ^ (row & 7)) << 3)];
            }
#pragma unroll
            for (int n = 0; n < 4; ++n) {
                const int row = n * 16 + c;
                vb[n] = *(const short8*)&bufV[row * 64 + (((kf * 4 + g) ^ (row & 7)) << 3)];
            }
#pragma unroll
            for (int i = 0; i < 4; ++i) {
#pragma unroll
                for (int n = 0; n < 4; ++n)
                    acc_o[i][n] = __builtin_amdgcn_mfma_f32_16x16x32_bf16(
                        pa[i], vb[n], acc_o[i][n], 0, 0, 0);
                acc_l[i] = __builtin_amdgcn_mfma_f32_16x16x32_bf16(
                    pa[i], ones, acc_l[i], 0, 0, 0);
            }
        }
    }

    const size_t obase = (size_t)b * SEQ * D_EMB + (size_t)h * HDIM;
#pragma unroll
    for (int i = 0; i < 4; ++i)
#pragma unroll
        for (int r = 0; r < 4; ++r) {
            const float rl = 1.f / acc_l[i][r];
            const int row = qi * 64 + i * 16 + g * 4 + r;
#pragma unroll
            for (int n = 0; n < 4; ++n) {
                const int col = n * 16 + c;
                ctx[obase + (size_t)row * D_EMB + col] =
                    __float2bfloat16(acc_o[i][n][r] * rl);
            }
        }
}

// ---------------------------------------------------------------------------
// launch
// ---------------------------------------------------------------------------
extern "C" void kernel_launch(void* const* d_in, const int* in_sizes, int n_in,
                              void* d_out, int out_size, void* d_ws, size_t ws_size,
                              hipStream_t stream)
{
    const float* x  = (const float*)d_in[0];
    const float* wq = (const float*)d_in[1];
    const float* wk = (const float*)d_in[2];
    const float* wv = (const float*)d_in[3];
    const float* wo = (const float*)d_in[4];
    const float* bo = (const float*)d_in[5];
    const float* w1 = (const float*)d_in[6];
    const float* b1 = (const float*)d_in[7];
    const float* w2 = (const float*)d_in[8];
    const float* b2 = (const float*)d_in[9];
    const float* g1  = (const float*)d_in[10];
    const float* be1 = (const float*)d_in[11];
    const float* g2  = (const float*)d_in[12];
    const float* be2 = (const float*)d_in[13];
    float* out = (float*)d_out;
    (void)in_sizes; (void)n_in; (void)out_size; (void)ws_size;

    // weight area [0,4MB): wqkv_t@0 (864K), wo_t@1M (288K), w1_t@1.5M (1.125M),
    // w2_t@2.75M (1.125M). slotA: h1/ctx/h2. slotB: qkv+vt / ff1.
    // x2 lives in d_out (written by oproj_ln, read by ff2 in-place).
    char* w = (char*)d_ws;
    bf16* wqkv_t = (bf16*)(w);
    bf16* wo_t   = (bf16*)(w + (size_t)(1024 * 1024));
    bf16* w1_t   = (bf16*)(w + (size_t)(1536 * 1024));
    bf16* w2_t   = (bf16*)(w + (size_t)(2816 * 1024));
    char* slotA  = w + 4 * 1024 * 1024;                          // 12.58 MB
    char* slotB  = slotA + (size_t)M_ROWS * D_EMB * sizeof(bf16);// 50.33 MB

    bf16* h1  = (bf16*)slotA;
    bf16* ctx = (bf16*)slotA;
    bf16* h2  = (bf16*)slotA;   // aliases ctx: oproj_ln writes only rows it reads
    bf16* qkv = (bf16*)slotB;
    bf16* vt  = (bf16*)slotB + (size_t)M_ROWS * DQKV;  // dead once ff1 written
    bf16* ff1 = (bf16*)slotB;

    const dim3 blk(256);

    // 0) weight prep (single dispatch)
    transpose_all<<<dim3(1728), dim3(32, 8), 0, stream>>>(
        wq, wk, wv, wo, w1, w2, wqkv_t, wo_t, w1_t, w2_t);

    // 1) h1 = LN(x)
    ln_kernel<<<dim3(M_ROWS / 4), blk, 0, stream>>>(x, g1, be1, h1);

    // 2) qkv = h1 @ [wq|wk|wv]; V tiles -> vt   (512-thread, 16 waves/CU)
    mfma_gemm<false, true, true><<<dim3(DQKV / 128, M_ROWS / 128), dim3(512), 0, stream>>>(
        h1, wqkv_t, nullptr, nullptr, qkv, M_ROWS, DQKV, D_EMB, vt);

    // 3) ctx = causal_attention(qkv, vt)
    attn_mfma<<<dim3(BATCH * NHEAD * 4), dim3(64), 0, stream>>>(qkv, vt, ctx);

    // 4) out(x2) = x + ctx @ wo + bo; h2 = LN(x2)  (fused, BM=32, 512 blocks)
    oproj_ln<<<dim3(M_ROWS / 32), blk, 0, stream>>>(
        ctx, wo_t, bo, x, g2, be2, out, h2);

    // 5) ff1 = relu(h2 @ w1 + b1)   (512-thread, 8-wave, 24 waves/CU)
    mfma_gemm64<true, true><<<dim3(DFF / 128, M_ROWS / 64), dim3(512), 0, stream>>>(
        h2, w1_t, b1, nullptr, ff1, M_ROWS, DFF, D_EMB);

    // 6) out += ff1 @ w2 + b2  (512-thread direct K=1536, in-place residual)
    mfma_gemm64<false, false><<<dim3(D_EMB / 128, M_ROWS / 64), dim3(512), 0, stream>>>(
        ff1, w2_t, b2, out, out, M_ROWS, D_EMB, DFF);
}

// Round 17
// 226.489 us; speedup vs baseline: 1.0449x; 1.0380x over previous
//
#include <hip/hip_runtime.h>
#include <hip/hip_bf16.h>

typedef __hip_bfloat16 bf16;
typedef __attribute__((ext_vector_type(8))) short short8;
typedef __attribute__((ext_vector_type(4))) float f32x4;

#define D_EMB 384
#define NHEAD 6
#define HDIM 64
#define SEQ 256
#define BATCH 64
#define M_ROWS (BATCH * SEQ)   // 16384
#define DFF (4 * D_EMB)        // 1536
#define DQKV (3 * D_EMB)       // 1152

__device__ __forceinline__ void async_load16(const void* gptr, void* lptr) {
    __builtin_amdgcn_global_load_lds(
        (const __attribute__((address_space(1))) unsigned int*)gptr,
        (__attribute__((address_space(3))) unsigned int*)lptr, 16, 0, 0);
}

// ---------------------------------------------------------------------------
// Combined weight prep: all six f32 [K,N] -> bf16 [N,K] transposes in ONE dispatch.
// ---------------------------------------------------------------------------
__global__ __launch_bounds__(256)
void transpose_all(const float* __restrict__ wq, const float* __restrict__ wk,
                   const float* __restrict__ wv, const float* __restrict__ wo,
                   const float* __restrict__ w1, const float* __restrict__ w2,
                   bf16* __restrict__ wqkv_t, bf16* __restrict__ wo_t,
                   bf16* __restrict__ w1_t, bf16* __restrict__ w2_t)
{
    __shared__ float t[32][33];
    const int id = blockIdx.x;
    const float* src; bf16* dst; int K, N, local, nbT;
    if      (id <  144) { src = wq; dst = wqkv_t;               K = 384;  N = 384;  local = id;        nbT = 12; }
    else if (id <  288) { src = wk; dst = wqkv_t + 147456;      K = 384;  N = 384;  local = id - 144;  nbT = 12; }
    else if (id <  432) { src = wv; dst = wqkv_t + 294912;      K = 384;  N = 384;  local = id - 288;  nbT = 12; }
    else if (id <  576) { src = wo; dst = wo_t;                 K = 384;  N = 384;  local = id - 432;  nbT = 12; }
    else if (id < 1152) { src = w1; dst = w1_t;                 K = 384;  N = 1536; local = id - 576;  nbT = 48; }
    else                { src = w2; dst = w2_t;                 K = 1536; N = 384;  local = id - 1152; nbT = 12; }
    const int nb = (local % nbT) * 32, kb = (local / nbT) * 32;
    const int tx = threadIdx.x, ty = threadIdx.y;
#pragma unroll
    for (int i = 0; i < 32; i += 8)
        t[ty + i][tx] = src[(size_t)(kb + ty + i) * N + nb + tx];
    __syncthreads();
#pragma unroll
    for (int i = 0; i < 32; i += 8)
        dst[(size_t)(nb + ty + i) * K + kb + tx] = __float2bfloat16(t[tx][ty + i]);
}

// ---------------------------------------------------------------------------
// LayerNorm: fp32 [M,384] -> bf16 [M,384]. One wave per row. (LN1 only.)
// ---------------------------------------------------------------------------
__global__ __launch_bounds__(256)
void ln_kernel(const float* __restrict__ x, const float* __restrict__ g,
               const float* __restrict__ be, bf16* __restrict__ out)
{
    const int row  = blockIdx.x * 4 + (threadIdx.x >> 6);
    const int lane = threadIdx.x & 63;
    const float* xr = x + (size_t)row * D_EMB;

    float v[6];
    float s = 0.f;
#pragma unroll
    for (int i = 0; i < 6; ++i) { v[i] = xr[lane + i * 64]; s += v[i]; }
#pragma unroll
    for (int off = 32; off; off >>= 1) s += __shfl_xor(s, off, 64);
    const float mean = s * (1.f / 384.f);

    float var = 0.f;
#pragma unroll
    for (int i = 0; i < 6; ++i) { float d = v[i] - mean; var += d * d; }
#pragma unroll
    for (int off = 32; off; off >>= 1) var += __shfl_xor(var, off, 64);
    const float rstd = rsqrtf(var * (1.f / 384.f) + 1e-5f);

    bf16* orow = out + (size_t)row * D_EMB;
#pragma unroll
    for (int i = 0; i < 6; ++i) {
        const int c = lane + i * 64;
        orow[c] = __float2bfloat16((v[i] - mean) * rstd * g[c] + be[c]);
    }
}

// ---------------------------------------------------------------------------
// MFMA GEMM (BM=128) at 512 threads / 8 waves (R23). 128x128 tile, 64 KB LDS,
// XOR swizzles, XCD chunked block swizzle. Used for qkv (VT path).
// ---------------------------------------------------------------------------
template<bool RELU, bool OUT_BF16, bool VT>
__global__ __launch_bounds__(512)
void mfma_gemm(const bf16* __restrict__ A, const bf16* __restrict__ Bt,
               const float* __restrict__ bias, const float* __restrict__ res,
               void* __restrict__ Cout, int M, int N, int K, bf16* __restrict__ vt)
{
    __shared__ __attribute__((aligned(16))) unsigned short smem[32768]; // 64 KB
    unsigned short* As = smem;           // [2][128*64]
    unsigned short* Bs = smem + 16384;   // [2][128*64]

    const int tid  = threadIdx.x;
    const int wave = tid >> 6;           // 0..7
    const int lane = tid & 63;

    // XCD-aware bijective chunked swizzle (nwg % 8 == 0 for all grids used)
    const int nwg = gridDim.x * gridDim.y;
    const int bl  = blockIdx.y * gridDim.x + blockIdx.x;
    const int lb  = (bl & 7) * (nwg >> 3) + (bl >> 3);
    const int m0  = (lb / gridDim.x) * 128;
    const int n0  = (lb % gridDim.x) * 128;

    const int wm = (wave >> 2) * 64;     // 0 or 64
    const int wn = (wave & 3) * 32;      // 0,32,64,96
    const int c16 = lane & 15;
    const int g   = lane >> 4;
    const int lr  = lane >> 3;
    const int ls  = lane & 7;

    f32x4 acc[4][2];
#pragma unroll
    for (int i = 0; i < 4; ++i)
#pragma unroll
        for (int j = 0; j < 2; ++j)
            acc[i][j] = (f32x4){0.f, 0.f, 0.f, 0.f};

    auto stage = [&](int buf, int k0) {
#pragma unroll
        for (int it = 0; it < 2; ++it) {
            const int r = (it * 8 + wave) * 8 + lr;       // rows 0..127
            const int oct = ls ^ (r & 7);
            async_load16(A + (size_t)(m0 + r) * K + k0 + oct * 8,
                         &As[buf * 8192 + (it * 8 + wave) * 512]);
            async_load16(Bt + (size_t)(n0 + r) * K + k0 + oct * 8,
                         &Bs[buf * 8192 + (it * 8 + wave) * 512]);
        }
    };

    stage(0, 0);
    const int KT = K >> 6;
    for (int kt = 0; kt < KT; ++kt) {
        const int cur = kt & 1;
        __syncthreads();
        if (kt + 1 < KT) stage(cur ^ 1, (kt + 1) * 64);
#pragma unroll
        for (int kk = 0; kk < 2; ++kk) {
            short8 af[4], bfr[2];
#pragma unroll
            for (int i = 0; i < 4; ++i) {
                const int row = wm + i * 16 + c16;
                af[i] = *(const short8*)&As[cur * 8192 + row * 64 + (((kk * 4 + g) ^ (row & 7)) << 3)];
            }
#pragma unroll
            for (int j = 0; j < 2; ++j) {
                const int row = wn + j * 16 + c16;
                bfr[j] = *(const short8*)&Bs[cur * 8192 + row * 64 + (((kk * 4 + g) ^ (row & 7)) << 3)];
            }
#pragma unroll
            for (int i = 0; i < 4; ++i)
#pragma unroll
                for (int j = 0; j < 2; ++j)
                    acc[i][j] = __builtin_amdgcn_mfma_f32_16x16x32_bf16(
                        af[i], bfr[j], acc[i][j], 0, 0, 0);
        }
    }

    const int crow = g * 4;

    if (VT && n0 >= 768) {
        // ---- V tile: LDS transpose (col-major, oct XOR-swizzled) -> vt
        __syncthreads();
        unsigned short* T = smem;            // 128*128 ushorts = 32 KB
#pragma unroll
        for (int j = 0; j < 2; ++j) {
            const int col = wn + j * 16 + c16;
#pragma unroll
            for (int i = 0; i < 4; ++i)
#pragma unroll
                for (int r = 0; r < 4; ++r) {
                    const int row = wm + i * 16 + crow + r;
                    bf16 pb = __float2bfloat16(acc[i][j][r]);
                    T[col * 128 + ((((row >> 3) ^ (col & 15)) << 3) | (row & 7))] =
                        *(unsigned short*)&pb;
                }
        }
        __syncthreads();
        const int b  = m0 >> 8;
        const int s0 = m0 & 255;
#pragma unroll
        for (int it = 0; it < 4; ++it) {
            const int cc = it * 512 + tid;                  // 0..2047
            const int col = cc >> 4, o = cc & 15;
            const int gcol = n0 - 768 + col;
            const int h = gcol >> 6, d = gcol & 63;
            const int so = (o ^ (col & 15)) << 3;
            const uint4 v = *(const uint4*)&T[col * 128 + o * 8];
            *(uint4*)(vt + (((size_t)(b * NHEAD + h) * 64 + d) * 256 + s0 + so)) = v;
        }
        return;
    }

    if (OUT_BF16) {
        // ---- coalesced bf16 epilogue via LDS restage
        __syncthreads();
        unsigned short* Cs = smem;           // 128*128 ushorts = 32 KB
#pragma unroll
        for (int j = 0; j < 2; ++j) {
            const int col = wn + j * 16 + c16;              // 0..127 in tile
            const float bv = bias ? bias[n0 + col] : 0.f;
#pragma unroll
            for (int i = 0; i < 4; ++i)
#pragma unroll
                for (int r = 0; r < 4; ++r) {
                    const int row = wm + i * 16 + crow + r;
                    float v = acc[i][j][r] + bv;
                    if (RELU) v = fmaxf(v, 0.f);
                    bf16 pb = __float2bfloat16(v);
                    Cs[row * 128 + ((((col >> 3) ^ (row & 15)) << 3) | (col & 7))] =
                        *(unsigned short*)&pb;
                }
        }
        __syncthreads();
#pragma unroll
        for (int it = 0; it < 4; ++it) {
            const int cc = it * 512 + tid;
            const int row = cc >> 4, o = cc & 15;
            const uint4 v = *(const uint4*)&Cs[row * 128 + ((o ^ (row & 15)) << 3)];
            *(uint4*)((bf16*)Cout + (size_t)(m0 + row) * N + n0 + o * 8) = v;
        }
        return;
    }

    // ---- f32 epilogue (sector-aligned). res may alias Cout.
#pragma unroll
    for (int j = 0; j < 2; ++j) {
        const int colg = n0 + wn + j * 16 + c16;
        const float bv = bias ? bias[colg] : 0.f;
#pragma unroll
        for (int i = 0; i < 4; ++i) {
            const int rowg = m0 + wm + i * 16 + crow;
#pragma unroll
            for (int r = 0; r < 4; ++r) {
                float v = acc[i][j][r] + bv;
                if (res) v += res[(size_t)(rowg + r) * N + colg];
                if (RELU) v = fmaxf(v, 0.f);
                ((float*)Cout)[(size_t)(rowg + r) * N + colg] = v;
            }
        }
    }
}

// ---------------------------------------------------------------------------
// mfma_gemm64 (R22): 512 threads / 8 waves, 64x128 tile, 48 KB LDS,
// 3 blocks/CU = 24 waves/CU. Used for ff1, ff2.
// res may alias Cout (in-place residual accumulate).
// ---------------------------------------------------------------------------
template<bool RELU, bool OUT_BF16>
__global__ __launch_bounds__(512)
void mfma_gemm64(const bf16* __restrict__ A, const bf16* __restrict__ Bt,
                 const float* __restrict__ bias, const float* __restrict__ res,
                 void* __restrict__ Cout, int M, int N, int K)
{
    __shared__ __attribute__((aligned(16))) unsigned short smem[24576]; // 48 KB
    unsigned short* As = smem;           // [2][64*64]  = 16 KB
    unsigned short* Bs = smem + 8192;    // [2][128*64] = 32 KB

    const int tid  = threadIdx.x;
    const int wave = tid >> 6;           // 0..7
    const int lane = tid & 63;

    const int nwg = gridDim.x * gridDim.y;
    const int bl  = blockIdx.y * gridDim.x + blockIdx.x;
    const int lb  = (bl & 7) * (nwg >> 3) + (bl >> 3);
    const int m0  = (lb / gridDim.x) * 64;
    const int n0  = (lb % gridDim.x) * 128;

    const int wm = (wave >> 2) * 32;     // 0 or 32
    const int wn = (wave & 3) * 32;      // 0,32,64,96
    const int c16 = lane & 15;
    const int g   = lane >> 4;
    const int lr  = lane >> 3;
    const int ls  = lane & 7;

    f32x4 acc[2][2];
#pragma unroll
    for (int i = 0; i < 2; ++i)
#pragma unroll
        for (int j = 0; j < 2; ++j)
            acc[i][j] = (f32x4){0.f, 0.f, 0.f, 0.f};

    // per-thread: 1 A load + 2 B loads per tile
    auto stage = [&](int buf, int k0) {
        {   // A rows 0..63: 8 waves x 8 rows
            const int r = wave * 8 + lr;
            const int oct = ls ^ (r & 7);
            async_load16(A + (size_t)(m0 + r) * K + k0 + oct * 8,
                         &As[buf * 4096 + wave * 512]);
        }
#pragma unroll
        for (int it = 0; it < 2; ++it) {  // B rows 0..127: 16 chunks x 8 rows
            const int r = (it * 8 + wave) * 8 + lr;
            const int oct = ls ^ (r & 7);
            async_load16(Bt + (size_t)(n0 + r) * K + k0 + oct * 8,
                         &Bs[buf * 8192 + (it * 8 + wave) * 512]);
        }
    };

    stage(0, 0);
    const int KT = K >> 6;
    for (int kt = 0; kt < KT; ++kt) {
        const int cur = kt & 1;
        __syncthreads();
        if (kt + 1 < KT) stage(cur ^ 1, (kt + 1) * 64);
#pragma unroll
        for (int kk = 0; kk < 2; ++kk) {
            short8 af[2], bfr[2];
#pragma unroll
            for (int i = 0; i < 2; ++i) {
                const int row = wm + i * 16 + c16;
                af[i] = *(const short8*)&As[cur * 4096 + row * 64 + (((kk * 4 + g) ^ (row & 7)) << 3)];
            }
#pragma unroll
            for (int j = 0; j < 2; ++j) {
                const int row = wn + j * 16 + c16;
                bfr[j] = *(const short8*)&Bs[cur * 8192 + row * 64 + (((kk * 4 + g) ^ (row & 7)) << 3)];
            }
#pragma unroll
            for (int i = 0; i < 2; ++i)
#pragma unroll
                for (int j = 0; j < 2; ++j)
                    acc[i][j] = __builtin_amdgcn_mfma_f32_16x16x32_bf16(
                        af[i], bfr[j], acc[i][j], 0, 0, 0);
        }
    }

    const int crow = g * 4;

    if (OUT_BF16) {
        // ---- coalesced bf16 epilogue via LDS restage (64x128 = 16 KB)
        __syncthreads();
        unsigned short* Cs = smem;
#pragma unroll
        for (int j = 0; j < 2; ++j) {
            const int col = wn + j * 16 + c16;              // 0..127
            const float bv = bias ? bias[n0 + col] : 0.f;
#pragma unroll
            for (int i = 0; i < 2; ++i)
#pragma unroll
                for (int r = 0; r < 4; ++r) {
                    const int row = wm + i * 16 + crow + r; // 0..63
                    float v = acc[i][j][r] + bv;
                    if (RELU) v = fmaxf(v, 0.f);
                    bf16 pb = __float2bfloat16(v);
                    Cs[row * 128 + ((((col >> 3) ^ (row & 15)) << 3) | (col & 7))] =
                        *(unsigned short*)&pb;
                }
        }
        __syncthreads();
#pragma unroll
        for (int it = 0; it < 2; ++it) {
            const int cc = it * 512 + tid;                  // 0..1023
            const int row = cc >> 4, o = cc & 15;
            const uint4 v = *(const uint4*)&Cs[row * 128 + ((o ^ (row & 15)) << 3)];
            *(uint4*)((bf16*)Cout + (size_t)(m0 + row) * N + n0 + o * 8) = v;
        }
        return;
    }

    // ---- f32 epilogue. res may alias Cout (in-place accumulate).
#pragma unroll
    for (int j = 0; j < 2; ++j) {
        const int colg = n0 + wn + j * 16 + c16;
        const float bv = bias ? bias[colg] : 0.f;
#pragma unroll
        for (int i = 0; i < 2; ++i) {
            const int rowg = m0 + wm + i * 16 + crow;
#pragma unroll
            for (int r = 0; r < 4; ++r) {
                float v = acc[i][j][r] + bv;
                if (res) v += res[(size_t)(rowg + r) * N + colg];
                if (RELU) v = fmaxf(v, 0.f);
                ((float*)Cout)[(size_t)(rowg + r) * N + colg] = v;
            }
        }
    }
}

// ---------------------------------------------------------------------------
// oproj_ln (R20): BM=32, grid 512 = 2 blocks/CU; B single-buffered 48 KB;
// BK=64 conflict-free 8-slot XOR scheme. Fuses o-proj + residual + LN2.
// ---------------------------------------------------------------------------
__global__ __launch_bounds__(256)
void oproj_ln(const bf16* __restrict__ A, const bf16* __restrict__ Bt,
              const float* __restrict__ bo, const float* __restrict__ x,
              const float* __restrict__ g2, const float* __restrict__ be2,
              float* __restrict__ out, bf16* __restrict__ h2)
{
    __shared__ __attribute__((aligned(16))) unsigned short smem[28672]; // 56 KB
    unsigned short* As = smem;            // [2][32*64]  = 8 KB
    unsigned short* Bs = smem + 4096;     // [1][384*64] = 48 KB
    __shared__ float lnred[32][4];        // {sum,sq} x {wn=0, wn=192}

    const int tid  = threadIdx.x;
    const int wave = tid >> 6;
    const int lane = tid & 63;

    const int nwg = gridDim.x;            // 512, %8==0
    const int bl  = blockIdx.x;
    const int lb  = (bl & 7) * (nwg >> 3) + (bl >> 3);
    const int m0  = lb * 32;

    const int wm  = (wave >> 1) * 16;     // 0 or 16
    const int wn  = (wave & 1) * 192;
    const int c16 = lane & 15;
    const int g   = lane >> 4;
    const int lr  = lane >> 3;
    const int ls  = lane & 7;

    f32x4 acc[12];
#pragma unroll
    for (int j = 0; j < 12; ++j)
        acc[j] = (f32x4){0.f, 0.f, 0.f, 0.f};

    auto stageA = [&](int buf, int k0) {
        const int r = wave * 8 + lr;
        const int oct = ls ^ (r & 7);
        async_load16(A + (size_t)(m0 + r) * D_EMB + k0 + oct * 8,
                     &As[buf * 2048 + wave * 512]);
    };
    auto stageB = [&](int k0) {
#pragma unroll
        for (int it = 0; it < 12; ++it) {                 // B rows 0..383
            const int r = (it * 4 + wave) * 8 + lr;
            const int oct = ls ^ (r & 7);
            async_load16(Bt + (size_t)r * D_EMB + k0 + oct * 8,
                         &Bs[(it * 4 + wave) * 512]);
        }
    };

    stageA(0, 0);
    stageB(0);
    const int KT = D_EMB >> 6;                            // 6
    for (int kt = 0; kt < KT; ++kt) {
        const int cur = kt & 1;
        __syncthreads();                                  // A[cur], B[kt] ready
        if (kt + 1 < KT) stageA(cur ^ 1, (kt + 1) * 64);  // A prefetch (dbuf)
#pragma unroll
        for (int kk = 0; kk < 2; ++kk) {
            short8 af, bfr[12];
            {
                const int row = wm + c16;                 // 0..31
                af = *(const short8*)&As[cur * 2048 + row * 64 + (((kk * 4 + g) ^ (row & 7)) << 3)];
            }
#pragma unroll
            for (int j = 0; j < 12; ++j) {
                const int row = wn + j * 16 + c16;
                bfr[j] = *(const short8*)&Bs[row * 64 + (((kk * 4 + g) ^ (row & 7)) << 3)];
            }
#pragma unroll
            for (int j = 0; j < 12; ++j)
                acc[j] = __builtin_amdgcn_mfma_f32_16x16x32_bf16(
                    af, bfr[j], acc[j], 0, 0, 0);
        }
        if (kt + 1 < KT) {
            __syncthreads();                              // readers done with B[kt]
            stageB((kt + 1) * 64);                        // overwrite B buffer
        }
    }

    // ---- epilogue: residual + bias -> out; row stats; LN -> h2
    const int crow = g * 4;
    float rsum[4], rsq[4];
#pragma unroll
    for (int r = 0; r < 4; ++r) { rsum[r] = 0.f; rsq[r] = 0.f; }

#pragma unroll
    for (int j = 0; j < 12; ++j) {
        const int col = wn + j * 16 + c16;
        const float bv = bo[col];
        const int rowg = m0 + wm + crow;
#pragma unroll
        for (int r = 0; r < 4; ++r) {
            float v = acc[j][r] + bv + x[(size_t)(rowg + r) * D_EMB + col];
            acc[j][r] = v;
            out[(size_t)(rowg + r) * D_EMB + col] = v;
            rsum[r] += v;
            rsq[r]  += v * v;
        }
    }

    // reduce across the 16 lanes (c16) sharing each row
#pragma unroll
    for (int off = 8; off; off >>= 1) {
#pragma unroll
        for (int r = 0; r < 4; ++r) {
            rsum[r] += __shfl_xor(rsum[r], off, 64);
            rsq[r]  += __shfl_xor(rsq[r], off, 64);
        }
    }
    const int half = (wave & 1) * 2;
    if (c16 == 0) {
#pragma unroll
        for (int r = 0; r < 4; ++r) {
            const int row = wm + crow + r;                // 0..31
            lnred[row][half + 0] = rsum[r];
            lnred[row][half + 1] = rsq[r];
        }
    }
    __syncthreads();

#pragma unroll
    for (int r = 0; r < 4; ++r) {
        const int row  = wm + crow + r;
        const float s  = lnred[row][0] + lnred[row][2];
        const float q  = lnred[row][1] + lnred[row][3];
        const float mean = s * (1.f / 384.f);
        const float var  = q * (1.f / 384.f) - mean * mean;
        const float rstd = rsqrtf(var + 1e-5f);
        const size_t rb = (size_t)(m0 + row) * D_EMB;
#pragma unroll
        for (int j = 0; j < 12; ++j) {
            const int col = wn + j * 16 + c16;
            h2[rb + col] = __float2bfloat16(
                (acc[j][r] - mean) * rstd * g2[col] + be2[col]);
        }
    }
}

// ---------------------------------------------------------------------------
// MFMA flash attention v3: one 64-thread block per (bh, qi), single-buffer
// 16 KB LDS -> 8 blocks/CU; TLP hides tile-load latency (dbuf and split
// waitcnt variants both refuted). XCD chunked swizzle colocates the 4 qi
// blocks of one (b,h) per XCD L2.
// ---------------------------------------------------------------------------
#define ATT_SCALE 0.18033688f   // (1/sqrt(64)) * log2(e)

__global__ __launch_bounds__(64, 2)
void attn_mfma(const bf16* __restrict__ qkv, const bf16* __restrict__ vt,
               bf16* __restrict__ ctx)
{
    __shared__ __attribute__((aligned(16))) unsigned short bufKP[4096];
    __shared__ __attribute__((aligned(16))) unsigned short bufV[4096];

    const int nb   = gridDim.x;
    const int bid0 = blockIdx.x;
    const int bid  = (bid0 & 7) * (nb >> 3) + (bid0 >> 3);
    const int bh = bid >> 2, qi = bid & 3;
    const int b = bh / NHEAD, h = bh % NHEAD;
    const int lane = threadIdx.x;
    const int g = lane >> 4;
    const int c = lane & 15;
    const int lr = lane >> 3;
    const int ls = lane & 7;

    const size_t qbase  = (size_t)b * SEQ * DQKV + (size_t)h * HDIM;
    const size_t vtbase = (size_t)bh * HDIM * SEQ;

    short8 qf[4][2];
#pragma unroll
    for (int i = 0; i < 4; ++i)
#pragma unroll
        for (int kf = 0; kf < 2; ++kf)
            qf[i][kf] = *(const short8*)(qkv + qbase +
                (size_t)(qi * 64 + i * 16 + c) * DQKV + kf * 32 + g * 8);

    short8 ones;
#pragma unroll
    for (int e = 0; e < 8; ++e) ones[e] = (short)0x3F80;

    f32x4 acc_o[4][4], acc_l[4];
#pragma unroll
    for (int i = 0; i < 4; ++i) {
        acc_l[i] = (f32x4){0.f, 0.f, 0.f, 0.f};
#pragma unroll
        for (int n = 0; n < 4; ++n)
            acc_o[i][n] = (f32x4){0.f, 0.f, 0.f, 0.f};
    }

    for (int jt = 0; jt <= qi; ++jt) {
#pragma unroll
        for (int it = 0; it < 8; ++it) {
            const int row = it * 8 + lr;
            const int oct = ls ^ (row & 7);
            async_load16(qkv + qbase + (size_t)(jt * 64 + row) * DQKV + D_EMB + oct * 8,
                         bufKP + it * 512);
            async_load16(vt + vtbase + (size_t)row * SEQ + jt * 64 + oct * 8,
                         bufV + it * 512);
        }
        asm volatile("s_waitcnt vmcnt(0)" ::: "memory");

        short8 kb[2][4];
#pragma unroll
        for (int kf = 0; kf < 2; ++kf)
#pragma unroll
            for (int j = 0; j < 4; ++j) {
                const int row = j * 16 + c;
                kb[kf][j] = *(const short8*)&bufKP[row * 64 + (((kf * 4 + g) ^ (row & 7)) << 3)];
            }

        const bool diag = (jt == qi);
#pragma unroll
        for (int i = 0; i < 4; ++i) {
            f32x4 s[4];
#pragma unroll
            for (int j = 0; j < 4; ++j) s[j] = (f32x4){0.f, 0.f, 0.f, 0.f};
#pragma unroll
            for (int kf = 0; kf < 2; ++kf)
#pragma unroll
                for (int j = 0; j < 4; ++j)
                    s[j] = __builtin_amdgcn_mfma_f32_16x16x32_bf16(
                        qf[i][kf], kb[kf][j], s[j], 0, 0, 0);

#pragma unroll
            for (int r = 0; r < 4; ++r) {
                const int row = i * 16 + g * 4 + r;
#pragma unroll
                for (int j = 0; j < 4; ++j) {
                    const int col = j * 16 + c;
                    float p = exp2f(s[j][r] * ATT_SCALE);
                    if (diag && col > row) p = 0.f;
                    bf16 pb = __float2bfloat16(p);
                    bufKP[row * 64 + (((col >> 3) ^ (row & 7)) << 3) + (col & 7)] =
                        *(unsigned short*)&pb;
                }
            }
        }

#pragma unroll
        for (int kf = 0; kf < 2; ++kf) {
            short8 pa[4], vb[4];
#pragma unroll
            for (int i = 0; i < 4; ++i) {
                const int row = i * 16 + c;
                pa[i] = *(const short8*)&bufKP[row * 64 + (((kf * 4 + g) ^ (row & 7)) << 3)];
            }
#pragma unroll
            for (int n = 0; n < 4; ++n) {
                const int row = n * 16 + c;
                vb[n] = *(const short8*)&bufV[row * 64 + (((kf * 4 + g) ^ (row & 7)) << 3)];
            }
#pragma unroll
            for (int i = 0; i < 4; ++i) {
#pragma unroll
                for (int n = 0; n < 4; ++n)
                    acc_o[i][n] = __builtin_amdgcn_mfma_f32_16x16x32_bf16(
                        pa[i], vb[n], acc_o[i][n], 0, 0, 0);
                acc_l[i] = __builtin_amdgcn_mfma_f32_16x16x32_bf16(
                    pa[i], ones, acc_l[i], 0, 0, 0);
            }
        }
    }

    const size_t obase = (size_t)b * SEQ * D_EMB + (size_t)h * HDIM;
#pragma unroll
    for (int i = 0; i < 4; ++i)
#pragma unroll
        for (int r = 0; r < 4; ++r) {
            const float rl = 1.f / acc_l[i][r];
            const int row = qi * 64 + i * 16 + g * 4 + r;
#pragma unroll
            for (int n = 0; n < 4; ++n) {
                const int col = n * 16 + c;
                ctx[obase + (size_t)row * D_EMB + col] =
                    __float2bfloat16(acc_o[i][n][r] * rl);
            }
        }
}

// ---------------------------------------------------------------------------
// launch
// ---------------------------------------------------------------------------
extern "C" void kernel_launch(void* const* d_in, const int* in_sizes, int n_in,
                              void* d_out, int out_size, void* d_ws, size_t ws_size,
                              hipStream_t stream)
{
    const float* x  = (const float*)d_in[0];
    const float* wq = (const float*)d_in[1];
    const float* wk = (const float*)d_in[2];
    const float* wv = (const float*)d_in[3];
    const float* wo = (const float*)d_in[4];
    const float* bo = (const float*)d_in[5];
    const float* w1 = (const float*)d_in[6];
    const float* b1 = (const float*)d_in[7];
    const float* w2 = (const float*)d_in[8];
    const float* b2 = (const float*)d_in[9];
    const float* g1  = (const float*)d_in[10];
    const float* be1 = (const float*)d_in[11];
    const float* g2  = (const float*)d_in[12];
    const float* be2 = (const float*)d_in[13];
    float* out = (float*)d_out;
    (void)in_sizes; (void)n_in; (void)out_size; (void)ws_size;

    // weight area [0,4MB): wqkv_t@0 (864K), wo_t@1M (288K), w1_t@1.5M (1.125M),
    // w2_t@2.75M (1.125M). slotA: h1/ctx/h2. slotB: qkv+vt / ff1.
    // x2 lives in d_out (written by oproj_ln, read by ff2 in-place).
    char* w = (char*)d_ws;
    bf16* wqkv_t = (bf16*)(w);
    bf16* wo_t   = (bf16*)(w + (size_t)(1024 * 1024));
    bf16* w1_t   = (bf16*)(w + (size_t)(1536 * 1024));
    bf16* w2_t   = (bf16*)(w + (size_t)(2816 * 1024));
    char* slotA  = w + 4 * 1024 * 1024;                          // 12.58 MB
    char* slotB  = slotA + (size_t)M_ROWS * D_EMB * sizeof(bf16);// 50.33 MB

    bf16* h1  = (bf16*)slotA;
    bf16* ctx = (bf16*)slotA;
    bf16* h2  = (bf16*)slotA;   // aliases ctx: oproj_ln writes only rows it reads
    bf16* qkv = (bf16*)slotB;
    bf16* vt  = (bf16*)slotB + (size_t)M_ROWS * DQKV;  // dead once ff1 written
    bf16* ff1 = (bf16*)slotB;

    const dim3 blk(256);

    // 0) weight prep (single dispatch)
    transpose_all<<<dim3(1728), dim3(32, 8), 0, stream>>>(
        wq, wk, wv, wo, w1, w2, wqkv_t, wo_t, w1_t, w2_t);

    // 1) h1 = LN(x)
    ln_kernel<<<dim3(M_ROWS / 4), blk, 0, stream>>>(x, g1, be1, h1);

    // 2) qkv = h1 @ [wq|wk|wv]; V tiles -> vt   (512-thread, 16 waves/CU)
    mfma_gemm<false, true, true><<<dim3(DQKV / 128, M_ROWS / 128), dim3(512), 0, stream>>>(
        h1, wqkv_t, nullptr, nullptr, qkv, M_ROWS, DQKV, D_EMB, vt);

    // 3) ctx = causal_attention(qkv, vt)
    attn_mfma<<<dim3(BATCH * NHEAD * 4), dim3(64), 0, stream>>>(qkv, vt, ctx);

    // 4) out(x2) = x + ctx @ wo + bo; h2 = LN(x2)  (fused, BM=32, 512 blocks)
    oproj_ln<<<dim3(M_ROWS / 32), blk, 0, stream>>>(
        ctx, wo_t, bo, x, g2, be2, out, h2);

    // 5) ff1 = relu(h2 @ w1 + b1)   (512-thread, 8-wave, 24 waves/CU)
    mfma_gemm64<true, true><<<dim3(DFF / 128, M_ROWS / 64), dim3(512), 0, stream>>>(
        h2, w1_t, b1, nullptr, ff1, M_ROWS, DFF, D_EMB);

    // 6) out += ff1 @ w2 + b2  (512-thread direct K=1536, in-place residual)
    mfma_gemm64<false, false><<<dim3(D_EMB / 128, M_ROWS / 64), dim3(512), 0, stream>>>(
        ff1, w2_t, b2, out, out, M_ROWS, D_EMB, DFF);
}